// Round 2
// baseline (1307.805 us; speedup 1.0000x reference)
//
#include <hip/hip_runtime.h>

#define NREL 3

// ===========================================================================
// Node-type tables for layer 0.  x0[i] is fully determined by
// (x_size[i], x_code[i]) -> ntype = ns*nc = 3030 distinct node types.
//   T[r][type][24]    = x0(type) @ W0_r          (873 KB, L2-resident)
//   Troot[type][24]   = x0(type) @ root0 + b0    (291 KB)
// ===========================================================================
__global__ void k_tables2(const float* __restrict__ size_emb,  // [ns,4]
                          const float* __restrict__ code_emb,  // [nc,32]
                          const float* __restrict__ w0,        // [3,36,24]
                          const float* __restrict__ root0,     // [36,24]
                          const float* __restrict__ b0,        // [24]
                          float* __restrict__ T, float* __restrict__ Troot,
                          int ns, int nc)
{
    int ntype = ns * nc;
    int tid = blockIdx.x * blockDim.x + threadIdx.x;
    int tot1 = NREL * ntype * 24;
    if (tid < tot1) {
        int d = tid % 24;
        int sc = (tid / 24) % ntype;
        int r = tid / (24 * ntype);
        int sz = sc / nc, cd = sc % nc;
        float a = 0.f;
        #pragma unroll
        for (int k = 0; k < 4; ++k)  a += size_emb[sz*4+k] * w0[(r*36+k)*24+d];
        for (int k = 0; k < 32; ++k) a += code_emb[cd*32+k] * w0[(r*36+4+k)*24+d];
        T[tid] = a;
    } else if (tid < tot1 + ntype * 24) {
        int t = tid - tot1;
        int d = t % 24;
        int sc = t / 24;
        int sz = sc / nc, cd = sc % nc;
        float a = b0[d];
        #pragma unroll
        for (int k = 0; k < 4; ++k)  a += size_emb[sz*4+k] * root0[k*24+d];
        for (int k = 0; k < 32; ++k) a += code_emb[cd*32+k] * root0[(4+k)*24+d];
        Troot[t] = a;
    }
}

__global__ void k_key(const int* __restrict__ x_size, const int* __restrict__ x_code,
                      int* __restrict__ key2, int n, int nc)
{
    int i = blockIdx.x * blockDim.x + threadIdx.x;
    if (i < n) key2[i] = x_size[i] * nc + x_code[i];
}

// ===========================================================================
// CSR build: count per (dst, rel) -> exclusive scan -> fill slots.
// slot.x = src(20b) | et<<20 (2b) | (dst & 255)<<22 (8b)   [n < 2^20]
// slot.y = 1/cnt[dst][et]
// ===========================================================================
__global__ void k_count(const int* __restrict__ dst, const int* __restrict__ et,
                        int* __restrict__ cntR, int E)
{
    int e = blockIdx.x * blockDim.x + threadIdx.x;
    if (e < E) atomicAdd(&cntR[dst[e]*3 + et[e]], 1);
}

__global__ void kscan1(const int* __restrict__ cntR, int* __restrict__ partials, int n)
{
    __shared__ int s[256];
    int t = threadIdx.x;
    int base = blockIdx.x * 1024 + t * 4;
    int sum = 0;
    #pragma unroll
    for (int j = 0; j < 4; ++j) {
        int node = base + j;
        if (node < n) sum += cntR[node*3] + cntR[node*3+1] + cntR[node*3+2];
    }
    s[t] = sum; __syncthreads();
    for (int off = 128; off > 0; off >>= 1) {
        if (t < off) s[t] += s[t + off];
        __syncthreads();
    }
    if (t == 0) partials[blockIdx.x] = s[0];
}

__global__ void kscan2(int* partials, int np)
{
    __shared__ int s[1024];
    int t = threadIdx.x;
    int v = (t < np) ? partials[t] : 0;
    s[t] = v; __syncthreads();
    for (int off = 1; off < 1024; off <<= 1) {
        int a = (t >= off) ? s[t - off] : 0;
        __syncthreads();
        s[t] += a; __syncthreads();
    }
    if (t < np) partials[t] = s[t] - v;  // exclusive
}

__global__ void kscan3(const int* __restrict__ cntR, const int* __restrict__ partials,
                       int* __restrict__ rowptr, int* __restrict__ rowfill, int n, int E)
{
    __shared__ int s[256];
    int t = threadIdx.x;
    int base = blockIdx.x * 1024 + t * 4;
    int d0 = 0, d1 = 0, d2 = 0, d3 = 0;
    if (base + 0 < n) d0 = cntR[(base+0)*3] + cntR[(base+0)*3+1] + cntR[(base+0)*3+2];
    if (base + 1 < n) d1 = cntR[(base+1)*3] + cntR[(base+1)*3+1] + cntR[(base+1)*3+2];
    if (base + 2 < n) d2 = cntR[(base+2)*3] + cntR[(base+2)*3+1] + cntR[(base+2)*3+2];
    if (base + 3 < n) d3 = cntR[(base+3)*3] + cntR[(base+3)*3+1] + cntR[(base+3)*3+2];
    int tsum = d0 + d1 + d2 + d3;
    s[t] = tsum; __syncthreads();
    for (int off = 1; off < 256; off <<= 1) {
        int a = (t >= off) ? s[t - off] : 0;
        __syncthreads();
        s[t] += a; __syncthreads();
    }
    int excl = s[t] - tsum + partials[blockIdx.x];
    if (base + 0 < n) { rowptr[base+0] = excl;            rowfill[base+0] = excl; }
    if (base + 1 < n) { rowptr[base+1] = excl+d0;         rowfill[base+1] = excl+d0; }
    if (base + 2 < n) { rowptr[base+2] = excl+d0+d1;      rowfill[base+2] = excl+d0+d1; }
    if (base + 3 < n) { rowptr[base+3] = excl+d0+d1+d2;   rowfill[base+3] = excl+d0+d1+d2; }
    if (blockIdx.x == 0 && t == 0) rowptr[n] = E;
}

__global__ void k_fill(const int* __restrict__ src, const int* __restrict__ dst,
                       const int* __restrict__ et, const int* __restrict__ cntR,
                       int* __restrict__ rowfill, uint2* __restrict__ edges, int E)
{
    int e = blockIdx.x * blockDim.x + threadIdx.x;
    if (e >= E) return;
    int d = dst[e]; int r = et[e];
    int pos = atomicAdd(&rowfill[d], 1);
    float scale = 1.0f / (float)cntR[d*3 + r];
    unsigned packed = (unsigned)src[e] | ((unsigned)r << 20) | ((unsigned)(d & 255) << 22);
    edges[pos] = make_uint2(packed, __float_as_uint(scale));
}

// ===========================================================================
// Layer 0, edge-parallel: per edge just a T-row lookup scaled into LDS acc.
// Block = 256 threads = 256 nodes; contiguous CSR edge range.
// ===========================================================================
__global__ void __launch_bounds__(256) k_layer0_ep(
    const int* __restrict__ key2,
    const int* __restrict__ rowptr, const uint2* __restrict__ edges,
    const float* __restrict__ T,      // [3*ntype*24]
    const float* __restrict__ Troot,  // [ntype*24]
    float* __restrict__ xout, int n, int ntype)
{
    __shared__ float acc[256 * 25];   // pad 24->25 (odd stride: banks spread)
    for (int t = threadIdx.x; t < 256 * 25; t += 256) acc[t] = 0.f;
    __syncthreads();

    int base = blockIdx.x * 256;
    int nend = min(base + 256, n);
    int estart = rowptr[base];
    int eend   = rowptr[nend];

    for (int e = estart + (int)threadIdx.x; e < eend; e += 256) {
        uint2 sl = edges[e];
        int s  = sl.x & 0xFFFFF;
        int r  = (sl.x >> 20) & 3;
        int dl = sl.x >> 22;
        float w = __uint_as_float(sl.y);
        const float4* trow = (const float4*)(T + ((size_t)r * ntype + key2[s]) * 24);
        float* arow = acc + dl * 25;
        #pragma unroll
        for (int q = 0; q < 6; ++q) {
            float4 v = trow[q];
            atomicAdd(&arow[q*4+0], v.x * w);
            atomicAdd(&arow[q*4+1], v.y * w);
            atomicAdd(&arow[q*4+2], v.z * w);
            atomicAdd(&arow[q*4+3], v.w * w);
        }
    }
    __syncthreads();

    int i = base + threadIdx.x;
    if (i >= n) return;
    const float* trr = Troot + (size_t)key2[i] * 24;
    const float* arow = acc + threadIdx.x * 25;
    float4* o = (float4*)(xout + (size_t)i * 24);
    #pragma unroll
    for (int q = 0; q < 6; ++q) {
        o[q] = make_float4(fmaxf(trr[q*4+0] + arow[q*4+0], 0.f),
                           fmaxf(trr[q*4+1] + arow[q*4+1], 0.f),
                           fmaxf(trr[q*4+2] + arow[q*4+2], 0.f),
                           fmaxf(trr[q*4+3] + arow[q*4+3], 0.f));
    }
}

// ===========================================================================
// Layers 1..3, aggregate-then-transform, edge-parallel:
//   edge phase:  acc[dst_local][r][0..DIN) += x[src]*scale   (LDS atomics,
//                NO weight access, no divergence)
//   transform:   out = relu(bias + x@root + sum_r agg_r @ W_r)
//                (weights read at uniform addresses -> L1 broadcast)
// NB nodes per 256-thread block; TPN=256/NB threads split DOUT.
// ===========================================================================
template<int DIN, int DOUT, int NB, bool FINAL>
__global__ void __launch_bounds__(256) k_layer_at(
    const float* __restrict__ xin,
    float* __restrict__ xout,
    const int* __restrict__ rowptr, const uint2* __restrict__ edges,
    const float* __restrict__ W,     // [3,DIN,DOUT]
    const float* __restrict__ root,  // [DIN,DOUT]
    const float* __restrict__ bias,  // [DOUT]
    const float* __restrict__ linw,  // [4,2]
    const float* __restrict__ linb,  // [2]
    float* __restrict__ finout, int n)
{
    constexpr int PAD = DIN + 1;              // odd stride -> banks spread
    __shared__ float acc[NB * 3 * PAD];
    for (int t = threadIdx.x; t < NB * 3 * PAD; t += 256) acc[t] = 0.f;
    __syncthreads();

    int base = blockIdx.x * NB;
    int nend = min(base + NB, n);
    int estart = rowptr[base];
    int eend   = rowptr[nend];

    for (int e = estart + (int)threadIdx.x; e < eend; e += 256) {
        uint2 sl = edges[e];
        int s  = sl.x & 0xFFFFF;
        int r  = (sl.x >> 20) & 3;
        int dl = (sl.x >> 22) & (NB - 1);     // NB divides 256
        float w = __uint_as_float(sl.y);
        const float4* p = (const float4*)(xin + (size_t)s * DIN);
        float* arow = acc + (dl * 3 + r) * PAD;
        #pragma unroll
        for (int q = 0; q < DIN / 4; ++q) {
            float4 v = p[q];
            atomicAdd(&arow[q*4+0], v.x * w);
            atomicAdd(&arow[q*4+1], v.y * w);
            atomicAdd(&arow[q*4+2], v.z * w);
            atomicAdd(&arow[q*4+3], v.w * w);
        }
    }
    __syncthreads();

    constexpr int TPN = 256 / NB;             // threads per node
    constexpr int DO2 = DOUT / TPN;           // outputs per thread
    int nl = threadIdx.x & (NB - 1);
    int dh = threadIdx.x / NB;                // which output chunk
    int i = base + nl;
    if (i >= n) return;

    float o[DO2];
    #pragma unroll
    for (int d = 0; d < DO2; ++d) o[d] = bias[dh*DO2 + d];

    {   // root part
        float xi[DIN];
        const float4* p = (const float4*)(xin + (size_t)i * DIN);
        #pragma unroll
        for (int q = 0; q < DIN / 4; ++q) {
            float4 v = p[q];
            xi[q*4+0]=v.x; xi[q*4+1]=v.y; xi[q*4+2]=v.z; xi[q*4+3]=v.w;
        }
        #pragma unroll
        for (int k = 0; k < DIN; ++k) {
            #pragma unroll
            for (int d = 0; d < DO2; ++d)
                o[d] = fmaf(xi[k], root[k*DOUT + dh*DO2 + d], o[d]);
        }
    }
    #pragma unroll
    for (int r = 0; r < NREL; ++r) {
        const float* arow = acc + (nl * 3 + r) * PAD;
        const float* wr = W + r*DIN*DOUT + dh*DO2;
        #pragma unroll
        for (int k = 0; k < DIN; ++k) {
            float a = arow[k];
            #pragma unroll
            for (int d = 0; d < DO2; ++d)
                o[d] = fmaf(a, wr[k*DOUT + d], o[d]);
        }
    }
    #pragma unroll
    for (int d = 0; d < DO2; ++d) o[d] = fmaxf(o[d], 0.f);

    if (FINAL) {                               // NB=256, DOUT=DO2=4
        float o0 = linb[0], o1 = linb[1];
        #pragma unroll
        for (int k = 0; k < 4; ++k) {
            o0 = fmaf(o[k], linw[k*2+0], o0);
            o1 = fmaf(o[k], linw[k*2+1], o1);
        }
        *(float2*)(finout + (size_t)i * 2) = make_float2(o0, o1);
    } else {
        float* op = xout + (size_t)i * DOUT + dh*DO2;
        #pragma unroll
        for (int q = 0; q < DO2 / 4; ++q)
            ((float4*)op)[q] = make_float4(o[q*4+0], o[q*4+1], o[q*4+2], o[q*4+3]);
    }
}

// ===========================================================================
extern "C" void kernel_launch(void* const* d_in, const int* in_sizes, int n_in,
                              void* d_out, int out_size, void* d_ws, size_t ws_size,
                              hipStream_t stream)
{
    const int*   x_code    = (const int*)d_in[0];
    const int*   x_size    = (const int*)d_in[1];
    const int*   edge_index= (const int*)d_in[2];
    const int*   edge_type = (const int*)d_in[3];
    const float* size_emb  = (const float*)d_in[4];
    const float* code_emb  = (const float*)d_in[5];
    const float* w0 = (const float*)d_in[6];  const float* root0 = (const float*)d_in[7];  const float* b0 = (const float*)d_in[8];
    const float* w1 = (const float*)d_in[9];  const float* root1 = (const float*)d_in[10]; const float* b1 = (const float*)d_in[11];
    const float* w2 = (const float*)d_in[12]; const float* root2 = (const float*)d_in[13]; const float* b2 = (const float*)d_in[14];
    const float* w3 = (const float*)d_in[15]; const float* root3 = (const float*)d_in[16]; const float* b3 = (const float*)d_in[17];
    const float* lin_w = (const float*)d_in[18];
    const float* lin_b = (const float*)d_in[19];

    int n  = in_sizes[0];
    int E  = in_sizes[3];
    int ns = in_sizes[4] / 4;    // 15
    int nc = in_sizes[5] / 32;   // 202
    int ntype = ns * nc;         // 3030
    const int* esrc = edge_index;
    const int* edst = edge_index + E;

    // workspace carve-up (~197 MB)
    char* ws = (char*)d_ws;
    size_t off = 0;
    auto alloc = [&](size_t bytes) -> void* {
        void* p = ws + off;
        off = (off + bytes + 255) & ~(size_t)255;
        return p;
    };
    float* bufA    = (float*)alloc((size_t)n * 24 * 4);       // x1, later x3
    float* bufB    = (float*)alloc((size_t)n * 16 * 4);       // x2 (key2 overlays)
    int*   rowptr  = (int*)  alloc(((size_t)n + 1) * 4);
    int*   rowfill = (int*)  alloc((size_t)n * 4);
    uint2* edges   = (uint2*)alloc((size_t)E * 8);
    int*   cntR    = (int*)  alloc((size_t)n * 3 * 4);
    int*   partials= (int*)  alloc(4096 * 4);
    float* T       = (float*)alloc((size_t)NREL * ntype * 24 * 4);
    float* Troot   = (float*)alloc((size_t)ntype * 24 * 4);
    // key2 lives in bufB: only needed before layer1 writes bufB
    int*   key2    = (int*)bufB;

    hipMemsetAsync(cntR, 0, (size_t)n * 3 * 4, stream);

    const int tb = 256;
    int tableThreads = NREL*ntype*24 + ntype*24;
    k_tables2<<<(tableThreads + tb - 1)/tb, tb, 0, stream>>>(
        size_emb, code_emb, w0, root0, b0, T, Troot, ns, nc);
    k_key<<<(n + tb - 1)/tb, tb, 0, stream>>>(x_size, x_code, key2, n, nc);

    k_count<<<(E + tb - 1)/tb, tb, 0, stream>>>(edst, edge_type, cntR, E);

    int nblk = (n + 1023) / 1024;   // 977 for n=1e6
    kscan1<<<nblk, 256, 0, stream>>>(cntR, partials, n);
    kscan2<<<1, 1024, 0, stream>>>(partials, nblk);
    kscan3<<<nblk, 256, 0, stream>>>(cntR, partials, rowptr, rowfill, n, E);

    k_fill<<<(E + tb - 1)/tb, tb, 0, stream>>>(esrc, edst, edge_type, cntR, rowfill, edges, E);

    int g256 = (n + 255) / 256;
    int g128 = (n + 127) / 128;
    k_layer0_ep<<<g256, tb, 0, stream>>>(key2, rowptr, edges, T, Troot, bufA, n, ntype);
    k_layer_at<24,16,128,false><<<g128, tb, 0, stream>>>(bufA, bufB, rowptr, edges,
                                                 w1, root1, b1, nullptr, nullptr, nullptr, n);
    k_layer_at<16, 8,128,false><<<g128, tb, 0, stream>>>(bufB, bufA, rowptr, edges,
                                                 w2, root2, b2, nullptr, nullptr, nullptr, n);
    k_layer_at< 8, 4,256,true ><<<g256, tb, 0, stream>>>(bufA, nullptr, rowptr, edges,
                                                 w3, root3, b3, lin_w, lin_b, (float*)d_out, n);
}

// Round 4
// 1211.772 us; speedup vs baseline: 1.0792x; 1.0792x over previous
//
#include <hip/hip_runtime.h>

#define NREL 3

// ===========================================================================
// Node-type tables for layer 0.  x0[i] is fully determined by
// (x_size[i], x_code[i]) -> ntype = ns*nc = 3030 distinct node types.
//   T[r][type][24]    = x0(type) @ W0_r          (873 KB, L2-resident)
//   Troot[type][24]   = x0(type) @ root0 + b0    (291 KB)
// ===========================================================================
__global__ void k_tables2(const float* __restrict__ size_emb,  // [ns,4]
                          const float* __restrict__ code_emb,  // [nc,32]
                          const float* __restrict__ w0,        // [3,36,24]
                          const float* __restrict__ root0,     // [36,24]
                          const float* __restrict__ b0,        // [24]
                          float* __restrict__ T, float* __restrict__ Troot,
                          int ns, int nc)
{
    int ntype = ns * nc;
    int tid = blockIdx.x * blockDim.x + threadIdx.x;
    int tot1 = NREL * ntype * 24;
    if (tid < tot1) {
        int d = tid % 24;
        int sc = (tid / 24) % ntype;
        int r = tid / (24 * ntype);
        int sz = sc / nc, cd = sc % nc;
        float a = 0.f;
        #pragma unroll
        for (int k = 0; k < 4; ++k)  a += size_emb[sz*4+k] * w0[(r*36+k)*24+d];
        for (int k = 0; k < 32; ++k) a += code_emb[cd*32+k] * w0[(r*36+4+k)*24+d];
        T[tid] = a;
    } else if (tid < tot1 + ntype * 24) {
        int t = tid - tot1;
        int d = t % 24;
        int sc = t / 24;
        int sz = sc / nc, cd = sc % nc;
        float a = b0[d];
        #pragma unroll
        for (int k = 0; k < 4; ++k)  a += size_emb[sz*4+k] * root0[k*24+d];
        for (int k = 0; k < 32; ++k) a += code_emb[cd*32+k] * root0[(4+k)*24+d];
        Troot[t] = a;
    }
}

__global__ void k_key(const int* __restrict__ x_size, const int* __restrict__ x_code,
                      int* __restrict__ key2, int n, int nc)
{
    int i = blockIdx.x * blockDim.x + threadIdx.x;
    if (i < n) key2[i] = x_size[i] * nc + x_code[i];
}

// ===========================================================================
// CSR build: count per (dst, rel) -> exclusive scan -> fill slots.
// slot.x = src(20b) | et<<20 (2b) | (dst & 255)<<22 (8b)   [n < 2^20]
// slot.y = 1/cnt[dst][et]
// ===========================================================================
__global__ void k_count(const int* __restrict__ dst, const int* __restrict__ et,
                        int* __restrict__ cntR, int E)
{
    int e = blockIdx.x * blockDim.x + threadIdx.x;
    if (e < E) atomicAdd(&cntR[dst[e]*3 + et[e]], 1);
}

__global__ void kscan1(const int* __restrict__ cntR, int* __restrict__ partials, int n)
{
    __shared__ int s[256];
    int t = threadIdx.x;
    int base = blockIdx.x * 1024 + t * 4;
    int sum = 0;
    #pragma unroll
    for (int j = 0; j < 4; ++j) {
        int node = base + j;
        if (node < n) sum += cntR[node*3] + cntR[node*3+1] + cntR[node*3+2];
    }
    s[t] = sum; __syncthreads();
    for (int off = 128; off > 0; off >>= 1) {
        if (t < off) s[t] += s[t + off];
        __syncthreads();
    }
    if (t == 0) partials[blockIdx.x] = s[0];
}

__global__ void kscan2(int* partials, int np)
{
    __shared__ int s[1024];
    int t = threadIdx.x;
    int v = (t < np) ? partials[t] : 0;
    s[t] = v; __syncthreads();
    for (int off = 1; off < 1024; off <<= 1) {
        int a = (t >= off) ? s[t - off] : 0;
        __syncthreads();
        s[t] += a; __syncthreads();
    }
    if (t < np) partials[t] = s[t] - v;  // exclusive
}

__global__ void kscan3(const int* __restrict__ cntR, const int* __restrict__ partials,
                       int* __restrict__ rowptr, int* __restrict__ rowfill, int n, int E)
{
    __shared__ int s[256];
    int t = threadIdx.x;
    int base = blockIdx.x * 1024 + t * 4;
    int d0 = 0, d1 = 0, d2 = 0, d3 = 0;
    if (base + 0 < n) d0 = cntR[(base+0)*3] + cntR[(base+0)*3+1] + cntR[(base+0)*3+2];
    if (base + 1 < n) d1 = cntR[(base+1)*3] + cntR[(base+1)*3+1] + cntR[(base+1)*3+2];
    if (base + 2 < n) d2 = cntR[(base+2)*3] + cntR[(base+2)*3+1] + cntR[(base+2)*3+2];
    if (base + 3 < n) d3 = cntR[(base+3)*3] + cntR[(base+3)*3+1] + cntR[(base+3)*3+2];
    int tsum = d0 + d1 + d2 + d3;
    s[t] = tsum; __syncthreads();
    for (int off = 1; off < 256; off <<= 1) {
        int a = (t >= off) ? s[t - off] : 0;
        __syncthreads();
        s[t] += a; __syncthreads();
    }
    int excl = s[t] - tsum + partials[blockIdx.x];
    if (base + 0 < n) { rowptr[base+0] = excl;            rowfill[base+0] = excl; }
    if (base + 1 < n) { rowptr[base+1] = excl+d0;         rowfill[base+1] = excl+d0; }
    if (base + 2 < n) { rowptr[base+2] = excl+d0+d1;      rowfill[base+2] = excl+d0+d1; }
    if (base + 3 < n) { rowptr[base+3] = excl+d0+d1+d2;   rowfill[base+3] = excl+d0+d1+d2; }
    if (blockIdx.x == 0 && t == 0) rowptr[n] = E;
}

__global__ void k_fill(const int* __restrict__ src, const int* __restrict__ dst,
                       const int* __restrict__ et, const int* __restrict__ cntR,
                       int* __restrict__ rowfill, uint2* __restrict__ edges, int E)
{
    int e = blockIdx.x * blockDim.x + threadIdx.x;
    if (e >= E) return;
    int d = dst[e]; int r = et[e];
    int pos = atomicAdd(&rowfill[d], 1);
    float scale = 1.0f / (float)cntR[d*3 + r];
    unsigned packed = (unsigned)src[e] | ((unsigned)r << 20) | ((unsigned)(d & 255) << 22);
    edges[pos] = make_uint2(packed, __float_as_uint(scale));
}

// ===========================================================================
// Layer 0, edge-parallel: per edge just a T-row lookup scaled into LDS acc.
// ===========================================================================
__global__ void __launch_bounds__(256) k_layer0_ep(
    const int* __restrict__ key2,
    const int* __restrict__ rowptr, const uint2* __restrict__ edges,
    const float* __restrict__ T,      // [3*ntype*24]
    const float* __restrict__ Troot,  // [ntype*24]
    float* __restrict__ xout, int n, int ntype)
{
    __shared__ float acc[256 * 25];   // pad 24->25 (odd stride: banks spread)
    for (int t = threadIdx.x; t < 256 * 25; t += 256) acc[t] = 0.f;
    __syncthreads();

    int base = blockIdx.x * 256;
    int nend = min(base + 256, n);
    int estart = rowptr[base];
    int eend   = rowptr[nend];

    for (int e = estart + (int)threadIdx.x; e < eend; e += 256) {
        uint2 sl = edges[e];
        int s  = sl.x & 0xFFFFF;
        int r  = (sl.x >> 20) & 3;
        int dl = sl.x >> 22;
        float w = __uint_as_float(sl.y);
        const float4* trow = (const float4*)(T + ((size_t)r * ntype + key2[s]) * 24);
        float* arow = acc + dl * 25;
        #pragma unroll
        for (int q = 0; q < 6; ++q) {
            float4 v = trow[q];
            atomicAdd(&arow[q*4+0], v.x * w);
            atomicAdd(&arow[q*4+1], v.y * w);
            atomicAdd(&arow[q*4+2], v.z * w);
            atomicAdd(&arow[q*4+3], v.w * w);
        }
    }
    __syncthreads();

    int i = base + threadIdx.x;
    if (i >= n) return;
    const float* trr = Troot + (size_t)key2[i] * 24;
    const float* arow = acc + threadIdx.x * 25;
    float4* o = (float4*)(xout + (size_t)i * 24);
    #pragma unroll
    for (int q = 0; q < 6; ++q) {
        o[q] = make_float4(fmaxf(trr[q*4+0] + arow[q*4+0], 0.f),
                           fmaxf(trr[q*4+1] + arow[q*4+1], 0.f),
                           fmaxf(trr[q*4+2] + arow[q*4+2], 0.f),
                           fmaxf(trr[q*4+3] + arow[q*4+3], 0.f));
    }
}

// ===========================================================================
// Layers 1..3, aggregate-then-transform.
//   edge phase:  acc[dst_local][r][0..DIN) += x[src]*scale  (LDS atomics)
//   transform:   weights read with WAVE-UNIFORM indices (dh readfirstlane'd)
//                -> compiler emits s_load; FMA uses SGPR operand slot.
//                Zero vector-memory and zero LDS traffic for weights.
// NB nodes/block (256 threads); TPN waves-groups split DOUT; TPN*NB == 256.
// ===========================================================================
template<int DIN, int DOUT, int NB, int TPN, bool FINAL>
__global__ void __launch_bounds__(256) k_layer_at(
    const float* __restrict__ xin,
    float* __restrict__ xout,
    const int* __restrict__ rowptr, const uint2* __restrict__ edges,
    const float* __restrict__ W,     // [3,DIN,DOUT]
    const float* __restrict__ root,  // [DIN,DOUT]
    const float* __restrict__ bias,  // [DOUT]
    const float* __restrict__ linw,  // [4,2]
    const float* __restrict__ linb,  // [2]
    float* __restrict__ finout, int n)
{
    constexpr int PAD = DIN + 1;              // dl-stride 3*PAD is odd -> banks spread
    __shared__ float acc[NB * 3 * PAD];
    for (int t = threadIdx.x; t < NB * 3 * PAD; t += 256) acc[t] = 0.f;
    __syncthreads();

    int base = blockIdx.x * NB;
    int nend = min(base + NB, n);
    int estart = rowptr[base];
    int eend   = rowptr[nend];

    for (int e = estart + (int)threadIdx.x; e < eend; e += 256) {
        uint2 sl = edges[e];
        int s  = sl.x & 0xFFFFF;
        int r  = (sl.x >> 20) & 3;
        int dl = (sl.x >> 22) & (NB - 1);     // NB divides 256
        float w = __uint_as_float(sl.y);
        const float4* p = (const float4*)(xin + (size_t)s * DIN);
        float* arow = acc + (dl * 3 + r) * PAD;
        #pragma unroll
        for (int q = 0; q < DIN / 4; ++q) {
            float4 v = p[q];
            atomicAdd(&arow[q*4+0], v.x * w);
            atomicAdd(&arow[q*4+1], v.y * w);
            atomicAdd(&arow[q*4+2], v.z * w);
            atomicAdd(&arow[q*4+3], v.w * w);
        }
    }
    __syncthreads();

    constexpr int DO2 = DOUT / TPN;           // outputs per thread
    int nl = threadIdx.x & (NB - 1);
    // NB >= 64  =>  threadIdx.x/NB is wave-uniform; readfirstlane makes the
    // compiler SEE that, so all weight/bias/root indices become SGPR-based
    // and lower to s_load (scalar pipe), not per-lane vector loads.
    int dh = __builtin_amdgcn_readfirstlane((int)threadIdx.x / NB);
    int i = base + nl;
    if (i >= n) return;

    float o[DO2];
    #pragma unroll
    for (int d = 0; d < DO2; ++d) o[d] = bias[dh*DO2 + d];

    {   // root part: self features (vector loads, coalesced)
        const float4* p = (const float4*)(xin + (size_t)i * DIN);
        #pragma unroll
        for (int q = 0; q < DIN / 4; ++q) {
            float4 v = p[q];
            #pragma unroll
            for (int j = 0; j < 4; ++j) {
                float xv = (&v.x)[j];
                #pragma unroll
                for (int d = 0; d < DO2; ++d)
                    o[d] = fmaf(xv, root[(q*4+j)*DOUT + dh*DO2 + d], o[d]);
            }
        }
    }
    #pragma unroll
    for (int r = 0; r < NREL; ++r) {
        const float* arow = acc + (nl * 3 + r) * PAD;
        #pragma unroll
        for (int k = 0; k < DIN; ++k) {
            float a = arow[k];
            #pragma unroll
            for (int d = 0; d < DO2; ++d)
                o[d] = fmaf(a, W[(r*DIN + k)*DOUT + dh*DO2 + d], o[d]);
        }
    }
    #pragma unroll
    for (int d = 0; d < DO2; ++d) o[d] = fmaxf(o[d], 0.f);

    if (FINAL) {                               // TPN=1, DOUT=DO2=4
        float o0 = linb[0], o1 = linb[1];
        #pragma unroll
        for (int k = 0; k < 4; ++k) {
            o0 = fmaf(o[k], linw[k*2+0], o0);
            o1 = fmaf(o[k], linw[k*2+1], o1);
        }
        *(float2*)(finout + (size_t)i * 2) = make_float2(o0, o1);
    } else {
        float* op = xout + (size_t)i * DOUT + dh*DO2;
        #pragma unroll
        for (int q = 0; q < DO2 / 4; ++q)
            ((float4*)op)[q] = make_float4(o[q*4+0], o[q*4+1], o[q*4+2], o[q*4+3]);
    }
}

// ===========================================================================
extern "C" void kernel_launch(void* const* d_in, const int* in_sizes, int n_in,
                              void* d_out, int out_size, void* d_ws, size_t ws_size,
                              hipStream_t stream)
{
    const int*   x_code    = (const int*)d_in[0];
    const int*   x_size    = (const int*)d_in[1];
    const int*   edge_index= (const int*)d_in[2];
    const int*   edge_type = (const int*)d_in[3];
    const float* size_emb  = (const float*)d_in[4];
    const float* code_emb  = (const float*)d_in[5];
    const float* w0 = (const float*)d_in[6];  const float* root0 = (const float*)d_in[7];  const float* b0 = (const float*)d_in[8];
    const float* w1 = (const float*)d_in[9];  const float* root1 = (const float*)d_in[10]; const float* b1 = (const float*)d_in[11];
    const float* w2 = (const float*)d_in[12]; const float* root2 = (const float*)d_in[13]; const float* b2 = (const float*)d_in[14];
    const float* w3 = (const float*)d_in[15]; const float* root3 = (const float*)d_in[16]; const float* b3 = (const float*)d_in[17];
    const float* lin_w = (const float*)d_in[18];
    const float* lin_b = (const float*)d_in[19];

    int n  = in_sizes[0];
    int E  = in_sizes[3];
    int ns = in_sizes[4] / 4;    // 15
    int nc = in_sizes[5] / 32;   // 202
    int ntype = ns * nc;         // 3030
    const int* esrc = edge_index;
    const int* edst = edge_index + E;

    // workspace carve-up (~197 MB)
    char* ws = (char*)d_ws;
    size_t off = 0;
    auto alloc = [&](size_t bytes) -> void* {
        void* p = ws + off;
        off = (off + bytes + 255) & ~(size_t)255;
        return p;
    };
    float* bufA    = (float*)alloc((size_t)n * 24 * 4);       // x1, later x3
    float* bufB    = (float*)alloc((size_t)n * 16 * 4);       // x2 (key2 overlays)
    int*   rowptr  = (int*)  alloc(((size_t)n + 1) * 4);
    int*   rowfill = (int*)  alloc((size_t)n * 4);
    uint2* edges   = (uint2*)alloc((size_t)E * 8);
    int*   cntR    = (int*)  alloc((size_t)n * 3 * 4);
    int*   partials= (int*)  alloc(4096 * 4);
    float* T       = (float*)alloc((size_t)NREL * ntype * 24 * 4);
    float* Troot   = (float*)alloc((size_t)ntype * 24 * 4);
    int*   key2    = (int*)bufB;   // only needed before layer1 writes bufB

    hipMemsetAsync(cntR, 0, (size_t)n * 3 * 4, stream);

    const int tb = 256;
    int tableThreads = NREL*ntype*24 + ntype*24;
    k_tables2<<<(tableThreads + tb - 1)/tb, tb, 0, stream>>>(
        size_emb, code_emb, w0, root0, b0, T, Troot, ns, nc);
    k_key<<<(n + tb - 1)/tb, tb, 0, stream>>>(x_size, x_code, key2, n, nc);

    k_count<<<(E + tb - 1)/tb, tb, 0, stream>>>(edst, edge_type, cntR, E);

    int nblk = (n + 1023) / 1024;   // 977 for n=1e6
    kscan1<<<nblk, 256, 0, stream>>>(cntR, partials, n);
    kscan2<<<1, 1024, 0, stream>>>(partials, nblk);
    kscan3<<<nblk, 256, 0, stream>>>(cntR, partials, rowptr, rowfill, n, E);

    k_fill<<<(E + tb - 1)/tb, tb, 0, stream>>>(esrc, edst, edge_type, cntR, rowfill, edges, E);

    int g256 = (n + 255) / 256;
    int g128 = (n + 127) / 128;
    k_layer0_ep<<<g256, tb, 0, stream>>>(key2, rowptr, edges, T, Troot, bufA, n, ntype);
    k_layer_at<24,16,128,2,false><<<g128, tb, 0, stream>>>(bufA, bufB, rowptr, edges,
                                                 w1, root1, b1, nullptr, nullptr, nullptr, n);
    k_layer_at<16, 8,128,2,false><<<g128, tb, 0, stream>>>(bufB, bufA, rowptr, edges,
                                                 w2, root2, b2, nullptr, nullptr, nullptr, n);
    k_layer_at< 8, 4,256,1,true ><<<g256, tb, 0, stream>>>(bufA, nullptr, rowptr, edges,
                                                 w3, root3, b3, lin_w, lin_b, (float*)d_out, n);
}

// Round 8
// 604.271 us; speedup vs baseline: 2.1643x; 2.0053x over previous
//
#include <hip/hip_runtime.h>

#define NREL 3

// ===========================================================================
// Node-type tables for layer 0.  x0[i] is fully determined by
// (x_size[i], x_code[i]) -> ntype = ns*nc = 3030 distinct node types.
//   T[r][type][24]    = x0(type) @ W0_r          (873 KB, L2-resident)
//   Troot[type][24]   = x0(type) @ root0 + b0    (291 KB)
// ===========================================================================
__global__ void k_tables2(const float* __restrict__ size_emb,  // [ns,4]
                          const float* __restrict__ code_emb,  // [nc,32]
                          const float* __restrict__ w0,        // [3,36,24]
                          const float* __restrict__ root0,     // [36,24]
                          const float* __restrict__ b0,        // [24]
                          float* __restrict__ T, float* __restrict__ Troot,
                          int ns, int nc)
{
    int ntype = ns * nc;
    int tid = blockIdx.x * blockDim.x + threadIdx.x;
    int tot1 = NREL * ntype * 24;
    if (tid < tot1) {
        int d = tid % 24;
        int sc = (tid / 24) % ntype;
        int r = tid / (24 * ntype);
        int sz = sc / nc, cd = sc % nc;
        float a = 0.f;
        #pragma unroll
        for (int k = 0; k < 4; ++k)  a += size_emb[sz*4+k] * w0[(r*36+k)*24+d];
        for (int k = 0; k < 32; ++k) a += code_emb[cd*32+k] * w0[(r*36+4+k)*24+d];
        T[tid] = a;
    } else if (tid < tot1 + ntype * 24) {
        int t = tid - tot1;
        int d = t % 24;
        int sc = t / 24;
        int sz = sc / nc, cd = sc % nc;
        float a = b0[d];
        #pragma unroll
        for (int k = 0; k < 4; ++k)  a += size_emb[sz*4+k] * root0[k*24+d];
        for (int k = 0; k < 32; ++k) a += code_emb[cd*32+k] * root0[(4+k)*24+d];
        Troot[t] = a;
    }
}

__global__ void k_key(const int* __restrict__ x_size, const int* __restrict__ x_code,
                      int* __restrict__ key2, int n, int nc)
{
    int i = blockIdx.x * blockDim.x + threadIdx.x;
    if (i < n) key2[i] = x_size[i] * nc + x_code[i];
}

// ===========================================================================
// CSR build: count per (dst, rel) -> exclusive scan -> fill slots.
// slot.x = src(20b) | et<<20 (2b)      [n < 2^20]
// slot.y = 1/cnt[dst][et]
// ===========================================================================
__global__ void k_count(const int* __restrict__ dst, const int* __restrict__ et,
                        int* __restrict__ cntR, int E)
{
    int e = blockIdx.x * blockDim.x + threadIdx.x;
    if (e < E) atomicAdd(&cntR[dst[e]*3 + et[e]], 1);
}

__global__ void kscan1(const int* __restrict__ cntR, int* __restrict__ partials, int n)
{
    __shared__ int s[256];
    int t = threadIdx.x;
    int base = blockIdx.x * 1024 + t * 4;
    int sum = 0;
    #pragma unroll
    for (int j = 0; j < 4; ++j) {
        int node = base + j;
        if (node < n) sum += cntR[node*3] + cntR[node*3+1] + cntR[node*3+2];
    }
    s[t] = sum; __syncthreads();
    for (int off = 128; off > 0; off >>= 1) {
        if (t < off) s[t] += s[t + off];
        __syncthreads();
    }
    if (t == 0) partials[blockIdx.x] = s[0];
}

__global__ void kscan2(int* partials, int np)
{
    __shared__ int s[1024];
    int t = threadIdx.x;
    int v = (t < np) ? partials[t] : 0;
    s[t] = v; __syncthreads();
    for (int off = 1; off < 1024; off <<= 1) {
        int a = (t >= off) ? s[t - off] : 0;
        __syncthreads();
        s[t] += a; __syncthreads();
    }
    if (t < np) partials[t] = s[t] - v;  // exclusive
}

__global__ void kscan3(const int* __restrict__ cntR, const int* __restrict__ partials,
                       int* __restrict__ rowptr, int* __restrict__ rowfill, int n, int E)
{
    __shared__ int s[256];
    int t = threadIdx.x;
    int base = blockIdx.x * 1024 + t * 4;
    int d0 = 0, d1 = 0, d2 = 0, d3 = 0;
    if (base + 0 < n) d0 = cntR[(base+0)*3] + cntR[(base+0)*3+1] + cntR[(base+0)*3+2];
    if (base + 1 < n) d1 = cntR[(base+1)*3] + cntR[(base+1)*3+1] + cntR[(base+1)*3+2];
    if (base + 2 < n) d2 = cntR[(base+2)*3] + cntR[(base+2)*3+1] + cntR[(base+2)*3+2];
    if (base + 3 < n) d3 = cntR[(base+3)*3] + cntR[(base+3)*3+1] + cntR[(base+3)*3+2];
    int tsum = d0 + d1 + d2 + d3;
    s[t] = tsum; __syncthreads();
    for (int off = 1; off < 256; off <<= 1) {
        int a = (t >= off) ? s[t - off] : 0;
        __syncthreads();
        s[t] += a; __syncthreads();
    }
    int excl = s[t] - tsum + partials[blockIdx.x];
    if (base + 0 < n) { rowptr[base+0] = excl;            rowfill[base+0] = excl; }
    if (base + 1 < n) { rowptr[base+1] = excl+d0;         rowfill[base+1] = excl+d0; }
    if (base + 2 < n) { rowptr[base+2] = excl+d0+d1;      rowfill[base+2] = excl+d0+d1; }
    if (base + 3 < n) { rowptr[base+3] = excl+d0+d1+d2;   rowfill[base+3] = excl+d0+d1+d2; }
    if (blockIdx.x == 0 && t == 0) rowptr[n] = E;
}

__global__ void k_fill(const int* __restrict__ src, const int* __restrict__ dst,
                       const int* __restrict__ et, const int* __restrict__ cntR,
                       int* __restrict__ rowfill, uint2* __restrict__ edges, int E)
{
    int e = blockIdx.x * blockDim.x + threadIdx.x;
    if (e >= E) return;
    int d = dst[e]; int r = et[e];
    int pos = atomicAdd(&rowfill[d], 1);
    float scale = 1.0f / (float)cntR[d*3 + r];
    unsigned packed = (unsigned)src[e] | ((unsigned)r << 20);
    edges[pos] = make_uint2(packed, __float_as_uint(scale));
}

// ===========================================================================
// Layer 0, PULL model: thread i owns node i; acc[24] in VGPRs.
//   out[i] = relu( Troot[key[i]] + sum_e T[r_e][key[src_e]] * scale_e )
// No LDS, no atomics.  T-row already folds W_r -> single accumulator.
// ===========================================================================
__global__ void __launch_bounds__(256) k_layer0_pull(
    const int* __restrict__ key2,
    const int* __restrict__ rowptr, const uint2* __restrict__ edges,
    const float* __restrict__ T,      // [3*ntype*24]
    const float* __restrict__ Troot,  // [ntype*24]
    float* __restrict__ xout, int n, int ntype)
{
    int i = blockIdx.x * blockDim.x + threadIdx.x;
    if (i >= n) return;

    float acc[24];
    {
        const float4* tr = (const float4*)(Troot + (size_t)key2[i] * 24);
        #pragma unroll
        for (int q = 0; q < 6; ++q) {
            float4 v = tr[q];
            acc[q*4+0]=v.x; acc[q*4+1]=v.y; acc[q*4+2]=v.z; acc[q*4+3]=v.w;
        }
    }
    int e0 = rowptr[i], e1 = rowptr[i+1];
    for (int e = e0; e < e1; ++e) {
        uint2 sl = edges[e];
        int s = sl.x & 0xFFFFF;
        int r = (sl.x >> 20) & 3;
        float w = __uint_as_float(sl.y);
        const float4* trow = (const float4*)(T + ((size_t)r * ntype + key2[s]) * 24);
        #pragma unroll
        for (int q = 0; q < 6; ++q) {
            float4 v = trow[q];
            acc[q*4+0] = fmaf(v.x, w, acc[q*4+0]);
            acc[q*4+1] = fmaf(v.y, w, acc[q*4+1]);
            acc[q*4+2] = fmaf(v.z, w, acc[q*4+2]);
            acc[q*4+3] = fmaf(v.w, w, acc[q*4+3]);
        }
    }
    float4* o = (float4*)(xout + (size_t)i * 24);
    #pragma unroll
    for (int q = 0; q < 6; ++q)
        o[q] = make_float4(fmaxf(acc[q*4+0], 0.f), fmaxf(acc[q*4+1], 0.f),
                           fmaxf(acc[q*4+2], 0.f), fmaxf(acc[q*4+3], 0.f));
}

// ===========================================================================
// Layers 1..3, PULL model: thread i owns node i.
//   edge loop: gather x[src] (DIN/4 float4), 3-way branch on r, accumulate
//              a_r[k] += x[k]*scale in VGPRs.  (branch, not index: keeps
//              accumulators in registers -- runtime-indexed arrays spill)
//   transform: o = bias + x[i]@root + sum_r a_r@W_r ; weight indices are
//              compile-time + uniform base -> s_load on scalar pipe.
// No LDS, no atomics.
// ===========================================================================
template<int DIN, int DOUT, bool FINAL>
__global__ void __launch_bounds__(256) k_layer_pull(
    const float* __restrict__ xin,
    float* __restrict__ xout,
    const int* __restrict__ rowptr, const uint2* __restrict__ edges,
    const float* __restrict__ W,     // [3,DIN,DOUT]
    const float* __restrict__ root,  // [DIN,DOUT]
    const float* __restrict__ bias,  // [DOUT]
    const float* __restrict__ linw,  // [4,2]
    const float* __restrict__ linb,  // [2]
    float* __restrict__ finout, int n)
{
    int i = blockIdx.x * blockDim.x + threadIdx.x;
    if (i >= n) return;

    float a0[DIN], a1[DIN], a2[DIN];
    #pragma unroll
    for (int k = 0; k < DIN; ++k) { a0[k] = 0.f; a1[k] = 0.f; a2[k] = 0.f; }

    int e0 = rowptr[i], e1 = rowptr[i+1];
    for (int e = e0; e < e1; ++e) {
        uint2 sl = edges[e];
        int s = sl.x & 0xFFFFF;
        int r = (sl.x >> 20) & 3;
        float w = __uint_as_float(sl.y);
        const float4* p = (const float4*)(xin + (size_t)s * DIN);
        float xs[DIN];
        #pragma unroll
        for (int q = 0; q < DIN/4; ++q) {
            float4 v = p[q];
            xs[q*4+0]=v.x; xs[q*4+1]=v.y; xs[q*4+2]=v.z; xs[q*4+3]=v.w;
        }
        if (r == 0) {
            #pragma unroll
            for (int k = 0; k < DIN; ++k) a0[k] = fmaf(xs[k], w, a0[k]);
        } else if (r == 1) {
            #pragma unroll
            for (int k = 0; k < DIN; ++k) a1[k] = fmaf(xs[k], w, a1[k]);
        } else {
            #pragma unroll
            for (int k = 0; k < DIN; ++k) a2[k] = fmaf(xs[k], w, a2[k]);
        }
    }

    float o[DOUT];
    #pragma unroll
    for (int d = 0; d < DOUT; ++d) o[d] = bias[d];

    {   // self/root term
        const float4* p = (const float4*)(xin + (size_t)i * DIN);
        #pragma unroll
        for (int q = 0; q < DIN/4; ++q) {
            float4 v = p[q];
            #pragma unroll
            for (int j = 0; j < 4; ++j) {
                float xv = (&v.x)[j];
                #pragma unroll
                for (int d = 0; d < DOUT; ++d)
                    o[d] = fmaf(xv, root[(q*4+j)*DOUT + d], o[d]);
            }
        }
    }
    #pragma unroll
    for (int k = 0; k < DIN; ++k) {
        #pragma unroll
        for (int d = 0; d < DOUT; ++d)
            o[d] = fmaf(a0[k], W[(0*DIN + k)*DOUT + d], o[d]);
    }
    #pragma unroll
    for (int k = 0; k < DIN; ++k) {
        #pragma unroll
        for (int d = 0; d < DOUT; ++d)
            o[d] = fmaf(a1[k], W[(1*DIN + k)*DOUT + d], o[d]);
    }
    #pragma unroll
    for (int k = 0; k < DIN; ++k) {
        #pragma unroll
        for (int d = 0; d < DOUT; ++d)
            o[d] = fmaf(a2[k], W[(2*DIN + k)*DOUT + d], o[d]);
    }
    #pragma unroll
    for (int d = 0; d < DOUT; ++d) o[d] = fmaxf(o[d], 0.f);

    if (FINAL) {                               // DOUT == 4
        float o0 = linb[0], o1 = linb[1];
        #pragma unroll
        for (int k = 0; k < 4; ++k) {
            o0 = fmaf(o[k], linw[k*2+0], o0);
            o1 = fmaf(o[k], linw[k*2+1], o1);
        }
        *(float2*)(finout + (size_t)i * 2) = make_float2(o0, o1);
    } else {
        float* op = xout + (size_t)i * DOUT;
        #pragma unroll
        for (int q = 0; q < DOUT/4; ++q)
            ((float4*)op)[q] = make_float4(o[q*4+0], o[q*4+1], o[q*4+2], o[q*4+3]);
    }
}

// ===========================================================================
extern "C" void kernel_launch(void* const* d_in, const int* in_sizes, int n_in,
                              void* d_out, int out_size, void* d_ws, size_t ws_size,
                              hipStream_t stream)
{
    const int*   x_code    = (const int*)d_in[0];
    const int*   x_size    = (const int*)d_in[1];
    const int*   edge_index= (const int*)d_in[2];
    const int*   edge_type = (const int*)d_in[3];
    const float* size_emb  = (const float*)d_in[4];
    const float* code_emb  = (const float*)d_in[5];
    const float* w0 = (const float*)d_in[6];  const float* root0 = (const float*)d_in[7];  const float* b0 = (const float*)d_in[8];
    const float* w1 = (const float*)d_in[9];  const float* root1 = (const float*)d_in[10]; const float* b1 = (const float*)d_in[11];
    const float* w2 = (const float*)d_in[12]; const float* root2 = (const float*)d_in[13]; const float* b2 = (const float*)d_in[14];
    const float* w3 = (const float*)d_in[15]; const float* root3 = (const float*)d_in[16]; const float* b3 = (const float*)d_in[17];
    const float* lin_w = (const float*)d_in[18];
    const float* lin_b = (const float*)d_in[19];

    int n  = in_sizes[0];
    int E  = in_sizes[3];
    int ns = in_sizes[4] / 4;    // 15
    int nc = in_sizes[5] / 32;   // 202
    int ntype = ns * nc;         // 3030
    const int* esrc = edge_index;
    const int* edst = edge_index + E;

    // workspace carve-up (~197 MB)
    char* ws = (char*)d_ws;
    size_t off = 0;
    auto alloc = [&](size_t bytes) -> void* {
        void* p = ws + off;
        off = (off + bytes + 255) & ~(size_t)255;
        return p;
    };
    float* bufA    = (float*)alloc((size_t)n * 24 * 4);       // x1, later x3
    float* bufB    = (float*)alloc((size_t)n * 16 * 4);       // x2 (key2 overlays)
    int*   rowptr  = (int*)  alloc(((size_t)n + 1) * 4);
    int*   rowfill = (int*)  alloc((size_t)n * 4);
    uint2* edges   = (uint2*)alloc((size_t)E * 8);
    int*   cntR    = (int*)  alloc((size_t)n * 3 * 4);
    int*   partials= (int*)  alloc(4096 * 4);
    float* T       = (float*)alloc((size_t)NREL * ntype * 24 * 4);
    float* Troot   = (float*)alloc((size_t)ntype * 24 * 4);
    int*   key2    = (int*)bufB;   // only needed before layer1 writes bufB

    hipMemsetAsync(cntR, 0, (size_t)n * 3 * 4, stream);

    const int tb = 256;
    int tableThreads = NREL*ntype*24 + ntype*24;
    k_tables2<<<(tableThreads + tb - 1)/tb, tb, 0, stream>>>(
        size_emb, code_emb, w0, root0, b0, T, Troot, ns, nc);
    k_key<<<(n + tb - 1)/tb, tb, 0, stream>>>(x_size, x_code, key2, n, nc);

    k_count<<<(E + tb - 1)/tb, tb, 0, stream>>>(edst, edge_type, cntR, E);

    int nblk = (n + 1023) / 1024;   // 977 for n=1e6
    kscan1<<<nblk, 256, 0, stream>>>(cntR, partials, n);
    kscan2<<<1, 1024, 0, stream>>>(partials, nblk);
    kscan3<<<nblk, 256, 0, stream>>>(cntR, partials, rowptr, rowfill, n, E);

    k_fill<<<(E + tb - 1)/tb, tb, 0, stream>>>(esrc, edst, edge_type, cntR, rowfill, edges, E);

    int g256 = (n + 255) / 256;
    k_layer0_pull<<<g256, tb, 0, stream>>>(key2, rowptr, edges, T, Troot, bufA, n, ntype);
    k_layer_pull<24,16,false><<<g256, tb, 0, stream>>>(bufA, bufB, rowptr, edges,
                                                 w1, root1, b1, nullptr, nullptr, nullptr, n);
    k_layer_pull<16, 8,false><<<g256, tb, 0, stream>>>(bufB, bufA, rowptr, edges,
                                                 w2, root2, b2, nullptr, nullptr, nullptr, n);
    k_layer_pull< 8, 4,true ><<<g256, tb, 0, stream>>>(bufA, nullptr, rowptr, edges,
                                                 w3, root3, b3, lin_w, lin_b, (float*)d_out, n);
}